// Round 9
// baseline (35.040 us; speedup 1.0000x reference)
//
#include <hip/hip_runtime.h>

// Problem constants (match reference)
#define BATCH 4
#define QLEN 2048
#define CLEN 2048
#define DIM 512
#define NSTRIPE 512         // K1 stripe blocks: b(4) x rowchunk(8) x colchunk(16)
#define NGEMM 256           // K1 Wcomb GEMM blocks: 16x16 tiles of 32x32
#define NRC 8               // row chunks per batch (256 rows each)

// The reference collapses: einsum 'bqkh,bvha->bqha' has independent k and v,
// and softmax over k sums to exactly 1, so
//   out[b,q,:] = ((sum_cl context[b,cl,:]) @ Wkv[:,D:2D]) @ Wout   for every q.
// query, Wq, mask are dead inputs.
//
// 2 kernels, 1 boundary. Key algebraic move: Wcomb = Wkv[:,D:] @ Wout is
// context-independent, so K1 computes {csum partials || Wcomb} concurrently,
// and K2 does reduce + per-f-slice matvec (redundant, L2-hot) + broadcast.
// In-kernel grid sync is 10-50x worse than a boundary on this chip (R3/4/7).

// ---- K1: 768 blocks, two roles ----
__global__ __launch_bounds__(256) void k1_stripe_gemm(
    const float* __restrict__ ctx, const float* __restrict__ Wkv,
    const float* __restrict__ Wout, float4* __restrict__ partial4,
    float* __restrict__ Wcomb)
{
    const int blk = blockIdx.x, t = threadIdx.x;
    if (blk < NSTRIPE) {
        // stripe: partial[b][rc][512] = colsum of rows rc*256..+256 (16.8MB read)
        __shared__ float4 red[256];
        const int b = blk >> 7, rc = (blk >> 4) & 7, cc = blk & 15;
        const int r0 = t >> 3, c = t & 7;          // 32 row-lanes x 8 f4 cols
        const size_t rowbase = (size_t)(b * CLEN + rc * 256 + r0) * (DIM / 4);
        const int f4 = cc * 8 + c;
        float4 s = make_float4(0.f, 0.f, 0.f, 0.f);
#pragma unroll
        for (int i = 0; i < 8; ++i) {              // rows r0 + 32*i
            float4 x = reinterpret_cast<const float4*>(ctx)
                           [rowbase + (size_t)(32 * i) * (DIM / 4) + f4];
            s.x += x.x; s.y += x.y; s.z += x.z; s.w += x.w;
        }
        red[t] = s;
        __syncthreads();
#pragma unroll
        for (int st = 128; st >= 8; st >>= 1) {    // reduce over the 32 row-lanes
            if (t < st) {
                float4 a = red[t], c4 = red[t + st];
                red[t] = make_float4(a.x + c4.x, a.y + c4.y, a.z + c4.z, a.w + c4.w);
            }
            __syncthreads();
        }
        if (t < 8)
            partial4[(size_t)(b * NRC + rc) * (DIM / 4) + cc * 8 + t] = red[t];
    } else {
        // GEMM: Wcomb[d][f] = sum_e Wkv[d][DIM+e] * Wout[e][f]; 32x32 tile
        __shared__ float As[32 * 64];              // 8 KB
        __shared__ float Bs[64 * 32];              // 8 KB
        const int m = blk - NSTRIPE;
        const int ti = m >> 4, tj = m & 15;
        const int j = t & 31, i0 = (t >> 5) * 4;
        float a0 = 0.f, a1 = 0.f, a2 = 0.f, a3 = 0.f;
        for (int e0 = 0; e0 < DIM; e0 += 64) {
#pragma unroll
            for (int it = 0; it < 8; ++it) {
                const int idx = it * 256 + t;
                As[idx] = Wkv[(size_t)(ti * 32 + (idx >> 6)) * (2 * DIM) + DIM + e0 + (idx & 63)];
                Bs[idx] = Wout[(size_t)(e0 + (idx >> 5)) * DIM + tj * 32 + (idx & 31)];
            }
            __syncthreads();
#pragma unroll 16
            for (int e = 0; e < 64; ++e) {
                const float bv = Bs[e * 32 + j];
                a0 += As[(i0 + 0) * 64 + e] * bv;
                a1 += As[(i0 + 1) * 64 + e] * bv;
                a2 += As[(i0 + 2) * 64 + e] * bv;
                a3 += As[(i0 + 3) * 64 + e] * bv;
            }
            __syncthreads();
        }
        float* dst = Wcomb + (size_t)(ti * 32 + i0) * DIM + tj * 32 + j;
        dst[0 * DIM] = a0; dst[1 * DIM] = a1; dst[2 * DIM] = a2; dst[3 * DIM] = a3;
    }
}

// ---- K2: 1024 blocks = b(4) x fslice(16, 32 f each) x qchunk(16, 128 q each).
// reduce 8 partials -> csum (LDS); matvec vs Wcomb panel; broadcast write. ----
__global__ __launch_bounds__(256) void k2_finish(
    const float* __restrict__ partial, const float* __restrict__ Wcomb,
    float4* __restrict__ out)
{
    __shared__ float cs[DIM];
    __shared__ float rr[256];
    __shared__ float os[32];
    const int blk = blockIdx.x, t = threadIdx.x;
    const int b = blk >> 8, fs = (blk >> 4) & 15, qc = blk & 15;

    // csum[b][:] from 8 row-chunk partials (16 KB L2-hot reads)
    {
        float s0 = 0.f, s1 = 0.f;
#pragma unroll
        for (int rc = 0; rc < NRC; ++rc) {
            const float* p = partial + (size_t)(b * NRC + rc) * DIM;
            s0 += p[t]; s1 += p[t + 256];
        }
        cs[t] = s0; cs[t + 256] = s1;
    }
    __syncthreads();

    // os[j] = sum_d cs[d] * Wcomb[d][fs*32+j]   (panel 64 KB, L2-hot)
    {
        const int j = t & 31, dg = t >> 5;
        const float* w = Wcomb + (size_t)(dg * 64) * DIM + fs * 32 + j;
        float s = 0.f;
#pragma unroll 8
        for (int k = 0; k < 64; ++k) s += cs[dg * 64 + k] * w[(size_t)k * DIM];
        rr[t] = s;
    }
    __syncthreads();
    if (t < 32) {
        float a = 0.f;
#pragma unroll
        for (int g = 0; g < 8; ++g) a += rr[g * 32 + t];
        os[t] = a;
    }
    __syncthreads();

    // broadcast: rows qc*128..+128, cols fs*32..+32 (8 f4)
    {
        const int c = t & 7, q0 = t >> 3;          // 32 q-lanes x 8 f4
        const float4 v = reinterpret_cast<const float4*>(os)[c];
        float4* dst = out + (size_t)(b * QLEN + qc * 128 + q0) * (DIM / 4) + fs * 8 + c;
#pragma unroll
        for (int i = 0; i < 4; ++i)
            dst[(size_t)(32 * i) * (DIM / 4)] = v;
    }
}

extern "C" void kernel_launch(void* const* d_in, const int* in_sizes, int n_in,
                              void* d_out, int out_size, void* d_ws, size_t ws_size,
                              hipStream_t stream) {
    // inputs: 0=query (unused), 1=context, 2=mask (unused), 3=Wq (unused), 4=Wkv, 5=Wout
    const float* ctx  = (const float*)d_in[1];
    const float* Wkv  = (const float*)d_in[4];
    const float* Wout = (const float*)d_in[5];
    float* ws = (float*)d_ws;
    float* partial = ws;                                  // BATCH*NRC*DIM = 64 KB
    float* Wcomb   = partial + BATCH * NRC * DIM;         // DIM*DIM = 1 MB
    // no memset: every ws word is written before it is read

    k1_stripe_gemm<<<NSTRIPE + NGEMM, 256, 0, stream>>>(ctx, Wkv, Wout,
                                                        (float4*)partial, Wcomb);
    k2_finish<<<1024, 256, 0, stream>>>(partial, Wcomb, (float4*)d_out);
}

// Round 10
// 28.985 us; speedup vs baseline: 1.2089x; 1.2089x over previous
//
#include <hip/hip_runtime.h>

// Problem constants (match reference)
#define BATCH 4
#define QLEN 2048
#define CLEN 2048
#define DIM 512
#define NCH 64              // chunks per batch (32 rows each)
#define NBLK1 (BATCH * NCH) // 256 K1 blocks (1/CU)
#define NSL 8               // e-slices in middle kernel

// The reference collapses: einsum 'bqkh,bvha->bqha' has independent k and v,
// and softmax over k sums to exactly 1, so
//   out[b,q,:] = ((sum_cl context[b,cl,:]) @ Wkv[:,D:2D]) @ Wout   for every q.
// query, Wq, mask are dead inputs.
//
// 3 kernels (boundary count is ~free: R6 5k=26.70, R8 3k=26.75, R9 2k=35).
// This round: fatter K1 partials (64/batch instead of 128-256) to shrink the
// middle kernel's serial column reduce; all access patterns wave-coalesced.

// ---- K1: partial[b][ch][d] = colsum of 32 context rows (16.8 MB read) ----
// 256 blocks, 1/CU; each thread sums 16 rows (16 independent 16B loads).
__global__ __launch_bounds__(256) void k1_partial(const float* __restrict__ ctx,
                                                  float4* __restrict__ partial) {
    __shared__ float4 red[256];
    const int blk = blockIdx.x, t = threadIdx.x;
    const int b = blk >> 6, ch = blk & 63;
    const int rg = t >> 7, f4 = t & 127;
    const float4* src = reinterpret_cast<const float4*>(ctx)
                      + (size_t)(b * CLEN + ch * 32 + rg) * (DIM / 4) + f4;
    float4 s0 = make_float4(0.f, 0.f, 0.f, 0.f);
    float4 s1 = make_float4(0.f, 0.f, 0.f, 0.f);
#pragma unroll
    for (int i = 0; i < 16; i += 2) {           // rows rg+2i: 16 loads, 2 streams
        float4 x = src[(size_t)(2 * i) * (DIM / 4)];
        float4 y = src[(size_t)(2 * i + 2) * (DIM / 4)];
        s0.x += x.x; s0.y += x.y; s0.z += x.z; s0.w += x.w;
        s1.x += y.x; s1.y += y.y; s1.z += y.z; s1.w += y.w;
    }
    red[t] = make_float4(s0.x + s1.x, s0.y + s1.y, s0.z + s1.z, s0.w + s1.w);
    __syncthreads();
    if (t < 128) {
        float4 a = red[t], c = red[t + 128];
        partial[(size_t)blk * (DIM / 4) + t] =
            make_float4(a.x + c.x, a.y + c.y, a.z + c.z, a.w + c.w);
    }
}

// ---- K2: 32 blocks = b(4) x sl(8). csum reduce (128 KB/block, coalesced),
// vsum e-slice, then its orow contribution opart[sl][b][:]. ----
__global__ __launch_bounds__(256) void k2_middle(const float4* __restrict__ partial4,
                                                 const float* __restrict__ Wkv,
                                                 const float* __restrict__ Wout,
                                                 float* __restrict__ opart) {
    __shared__ float4 csh[2][128];
    __shared__ float cs[DIM];
    __shared__ float vl[256];
    __shared__ float vslice[64];
    const int blk = blockIdx.x, t = threadIdx.x;
    const int b = blk >> 3, sl = blk & 7;

    // csum: 64 chunks split over 2 thread-halves; 1 KB/wave coalesced reads
    {
        const int f4 = t & 127, h = t >> 7;
        const float4* p = partial4 + (size_t)(b * NCH + h * 32) * (DIM / 4) + f4;
        float4 s = make_float4(0.f, 0.f, 0.f, 0.f);
#pragma unroll 8
        for (int ch = 0; ch < 32; ++ch) {
            float4 x = p[(size_t)ch * (DIM / 4)];
            s.x += x.x; s.y += x.y; s.z += x.z; s.w += x.w;
        }
        csh[h][f4] = s;
    }
    __syncthreads();
    if (t < 128) {
        float4 a = csh[0][t], c = csh[1][t];
        reinterpret_cast<float4*>(cs)[t] =
            make_float4(a.x + c.x, a.y + c.y, a.z + c.z, a.w + c.w);
    }
    __syncthreads();

    // vslice[el] = sum_d cs[d] * Wkv[d][DIM + sl*64 + el]
    {
        const int el = t & 63, dg = t >> 6;
        const float* w = Wkv + (size_t)(dg * 128) * (2 * DIM) + DIM + sl * 64 + el;
        float s = 0.f;
#pragma unroll 8
        for (int d0 = 0; d0 < 128; ++d0)
            s += cs[dg * 128 + d0] * w[(size_t)d0 * (2 * DIM)];
        vl[t] = s;
    }
    __syncthreads();
    if (t < 64) vslice[t] = vl[t] + vl[t + 64] + vl[t + 128] + vl[t + 192];
    __syncthreads();

    // opart[sl][b][f] = sum_{e in slice} vslice[e] * Wout[sl*64+e][f]
#pragma unroll
    for (int half = 0; half < 2; ++half) {
        const int f = half * 256 + t;
        const float* w = Wout + (size_t)(sl * 64) * DIM + f;
        float s = 0.f;
#pragma unroll 8
        for (int e0 = 0; e0 < 64; ++e0) s += vslice[e0] * w[(size_t)e0 * DIM];
        opart[(size_t)(sl * BATCH + b) * DIM + f] = s;
    }
}

// ---- K3: out[b,q,:] = sum_sl opart[sl][b][:] for all q (16.8 MB write) ----
__global__ __launch_bounds__(256) void k3_bcast(const float4* __restrict__ opart4,
                                                float4* __restrict__ out) {
    const int blk = blockIdx.x, t = threadIdx.x;
    const int b = blk >> 8, qg = blk & 255;
    const int rg = t >> 7, f4 = t & 127;
    float4 v = make_float4(0.f, 0.f, 0.f, 0.f);
#pragma unroll
    for (int sl = 0; sl < NSL; ++sl) {           // 8 independent L2-hot loads
        float4 x = opart4[(size_t)(sl * BATCH + b) * (DIM / 4) + f4];
        v.x += x.x; v.y += x.y; v.z += x.z; v.w += x.w;
    }
    float4* dst = out + (size_t)(b * QLEN + qg * 8) * (DIM / 4);
#pragma unroll
    for (int i = 0; i < 4; ++i)
        dst[(size_t)(rg + 2 * i) * (DIM / 4) + f4] = v;
}

extern "C" void kernel_launch(void* const* d_in, const int* in_sizes, int n_in,
                              void* d_out, int out_size, void* d_ws, size_t ws_size,
                              hipStream_t stream) {
    // inputs: 0=query (unused), 1=context, 2=mask (unused), 3=Wq (unused), 4=Wkv, 5=Wout
    const float* ctx  = (const float*)d_in[1];
    const float* Wkv  = (const float*)d_in[4];
    const float* Wout = (const float*)d_in[5];
    float* ws = (float*)d_ws;
    float* partial = ws;                                   // NBLK1*DIM = 512 KB
    float* opart   = partial + (size_t)NBLK1 * DIM;        // NSL*BATCH*DIM = 64 KB
    // no memset: every ws word is written before it is read

    k1_partial<<<NBLK1, 256, 0, stream>>>(ctx, (float4*)partial);
    k2_middle<<<BATCH * NSL, 256, 0, stream>>>((const float4*)partial, Wkv, Wout, opart);
    k3_bcast<<<BATCH * 256, 256, 0, stream>>>((const float4*)opart, (float4*)d_out);
}